// Round 6
// baseline (831.414 us; speedup 1.0000x reference)
//
#include <hip/hip_runtime.h>
#include <math.h>

#define N_NODES  50000
#define N_EDGES  800000
#define N_GRAPHS 500
#define NH       16
#define MHID     256
#define RN       128
#define RO       32
#define DDEG     6

typedef unsigned short ushort_t;
typedef __attribute__((ext_vector_type(8))) short short8;
typedef __attribute__((ext_vector_type(4))) float f32x4;

__device__ __forceinline__ float selu_f(float v) {
    const float scale = 1.0507009873554805f;
    const float alpha = 1.6732632423543772f;
    return v > 0.f ? scale * v : scale * alpha * (expf(v) - 1.f);
}
__device__ __forceinline__ float sigmoid_f(float v) { return 1.f / (1.f + expf(-v)); }
__device__ __forceinline__ ushort_t bf_rne(float v) {
    unsigned u = __float_as_uint(v);
    return (ushort_t)((u + 0x7fffu + ((u >> 16) & 1u)) >> 16);
}
__device__ __forceinline__ float bf_tof(ushort_t s) {
    return __uint_as_float(((unsigned)s) << 16);
}
#define MFMA16(a, b, c) __builtin_amdgcn_mfma_f32_16x16x32_bf16(a, b, c, 0, 0, 0)

// ---------------------------------------------------------------------------
// blocks 0..6: exact MLP eval at nodes e=k/6 -> aT[7][256], beT[7][16].
// blocks 7..70: transpose+split W_R, W_j2 into bf16 hi/lo [j][k] for MFMA B.
// ---------------------------------------------------------------------------
__global__ void build_and_prep(const float* __restrict__ W_l1, const float* __restrict__ b_l1,
                               const float* __restrict__ W_l2, const float* __restrict__ b_l2,
                               const float* __restrict__ W_b1, const float* __restrict__ b_b1,
                               const float* __restrict__ W_b2, const float* __restrict__ b_b2,
                               const float* __restrict__ W_R, const float* __restrict__ W_j2,
                               float* __restrict__ aT, float* __restrict__ beT,
                               ushort_t* __restrict__ WRh, ushort_t* __restrict__ WRl,
                               ushort_t* __restrict__ WJh, ushort_t* __restrict__ WJl) {
    __shared__ float hid[MHID];
    __shared__ float hidb[MHID];
    int j = threadIdx.x;
    if (blockIdx.x < 7) {
        int t = blockIdx.x;
        float ev = (float)t / 6.0f;
        hid[j]  = selu_f(ev * W_l1[j] + b_l1[j]);
        hidb[j] = selu_f(ev * W_b1[j] + b_b1[j]);
        __syncthreads();
        float acc = b_l2[j];
        for (int k = 0; k < MHID; ++k)
            acc += hid[k] * W_l2[k * 256 + j];
        aT[t * 256 + j] = acc;
        if (j < NH) {
            float accb = b_b2[j];
            for (int k = 0; k < MHID; ++k)
                accb += hidb[k] * W_b2[k * NH + j];
            beT[t * NH + j] = accb;
        }
    } else {
        int g = (blockIdx.x - 7) * 256 + j;     // 0..16383
        int jj = g >> 7, kk = g & 127;
        float v = W_R[kk * 128 + jj];
        ushort_t h = bf_rne(v);
        WRh[jj * 128 + kk] = h;
        WRl[jj * 128 + kk] = bf_rne(v - bf_tof(h));
        v = W_j2[kk * 128 + jj];
        h = bf_rne(v);
        WJh[jj * 128 + kk] = h;
        WJl[jj * 128 + kk] = bf_rne(v - bf_tof(h));
    }
}

// Newton divided-difference coefficients over nodes k/6.
__global__ void newton_coeffs(const float* __restrict__ aT, const float* __restrict__ beT,
                              float* __restrict__ C, float* __restrict__ beC) {
    int j = threadIdx.x;
    float y[7];
    #pragma unroll
    for (int k = 0; k < 7; ++k) y[k] = aT[k * 256 + j];
    #pragma unroll
    for (int lvl = 1; lvl <= DDEG; ++lvl)
        #pragma unroll
        for (int k = DDEG; k >= 1; --k)
            if (k >= lvl) y[k] = (y[k] - y[k - 1]) * (6.0f / (float)lvl);
    #pragma unroll
    for (int p = 0; p < 7; ++p) C[p * 256 + j] = y[p];

    if (j < NH) {
        float z[7];
        #pragma unroll
        for (int k = 0; k < 7; ++k) z[k] = beT[k * NH + j];
        #pragma unroll
        for (int lvl = 1; lvl <= DDEG; ++lvl)
            #pragma unroll
            for (int k = DDEG; k >= 1; --k)
                if (k >= lvl) z[k] = (z[k] - z[k - 1]) * (6.0f / (float)lvl);
        #pragma unroll
        for (int p = 0; p < 7; ++p) beC[p * NH + j] = z[p];
    }
}

__global__ void init_h(const float* __restrict__ x, float* __restrict__ h) {
    int n = blockIdx.x * blockDim.x + threadIdx.x;
    if (n >= N_NODES) return;
    float4* hp = (float4*)(h + (size_t)n * 16);
    hp[0] = make_float4(x[n * 2 + 0], x[n * 2 + 1], 0.f, 0.f);
    hp[1] = make_float4(0.f, 0.f, 0.f, 0.f);
    hp[2] = make_float4(0.f, 0.f, 0.f, 0.f);
    hp[3] = make_float4(0.f, 0.f, 0.f, 0.f);
}

// ---------------------------------------------------------------------------
// CSR-by-destination build + degree-sorted node permutation
// ---------------------------------------------------------------------------
__global__ void count_deg(const int* __restrict__ second, int* __restrict__ deg) {
    int i = blockIdx.x * blockDim.x + threadIdx.x;
    if (i < N_EDGES) atomicAdd(&deg[second[i]], 1);
}

// scan1 + degree histogram (dh pre-zeroed with deg)
__global__ void scan1(const int* __restrict__ deg, int* __restrict__ incl, int* __restrict__ bsum,
                      int* __restrict__ dh) {
    __shared__ int s[256];
    int t = threadIdx.x, i = blockIdx.x * 256 + t;
    int v = (i < N_NODES) ? deg[i] : 0;
    if (i < N_NODES) atomicAdd(&dh[min(v, 63)], 1);
    s[t] = v;
    __syncthreads();
    for (int d = 1; d < 256; d <<= 1) {
        int add = (t >= d) ? s[t - d] : 0;
        __syncthreads();
        s[t] += add;
        __syncthreads();
    }
    if (i < N_NODES) incl[i] = s[t];
    if (t == 255) bsum[blockIdx.x] = s[255];
}

// scan2 (block sums) + exclusive scan of degree histogram -> dcur
__global__ void scan2(const int* __restrict__ bsum, int* __restrict__ bpre, int nblk,
                      const int* __restrict__ dh, int* __restrict__ dcur) {
    __shared__ int s[256];
    int t = threadIdx.x;
    int v = (t < nblk) ? bsum[t] : 0;
    s[t] = v;
    __syncthreads();
    for (int d = 1; d < 256; d <<= 1) {
        int add = (t >= d) ? s[t - d] : 0;
        __syncthreads();
        s[t] += add;
        __syncthreads();
    }
    if (t < nblk) bpre[t] = s[t] - v;   // exclusive
    __syncthreads();
    int hv = (t < 64) ? dh[t] : 0;
    s[t] = hv;
    __syncthreads();
    for (int d = 1; d < 64; d <<= 1) {
        int add = (t >= d && t < 64) ? s[t - d] : 0;
        __syncthreads();
        if (t < 64) s[t] += add;
        __syncthreads();
    }
    if (t < 64) dcur[t] = s[t] - hv;    // exclusive
}

// scan3 (CSR offsets) + degree-sort scatter -> perm
__global__ void scan3(const int* __restrict__ incl, const int* __restrict__ deg,
                      const int* __restrict__ bpre, int* __restrict__ off, int* __restrict__ cursor,
                      int* __restrict__ dcur, int* __restrict__ perm) {
    int i = blockIdx.x * 256 + threadIdx.x;
    if (i < N_NODES) {
        int o = bpre[blockIdx.x] + incl[i] - deg[i];
        off[i] = o;
        cursor[i] = o;
        int b = min(deg[i], 63);
        int p = atomicAdd(&dcur[b], 1);
        perm[p] = i;
    }
    if (i == 0) off[N_NODES] = N_EDGES;
}

// em word = (first << 16) | round(e * 65535)
__global__ void scatter_edges(const float* __restrict__ e, const int* __restrict__ first,
                              const int* __restrict__ second, int* __restrict__ cursor,
                              unsigned* __restrict__ em) {
    int i = blockIdx.x * blockDim.x + threadIdx.x;
    if (i >= N_EDGES) return;
    int d = second[i];
    int slot = atomicAdd(&cursor[d], 1);
    unsigned e16 = (unsigned)(e[i] * 65535.f + 0.5f);
    em[slot] = ((unsigned)first[i] << 16) | e16;
}

// Pass-invariant be aggregate (once).
__global__ void mbe_pass(const float* __restrict__ beC, const unsigned* __restrict__ em,
                         const int* __restrict__ off, const int* __restrict__ perm,
                         float* __restrict__ mBE) {
    int lane = threadIdx.x & 15;
    int grp  = threadIdx.x >> 4;
    int n = perm[blockIdx.x * 16 + grp];
    float c0 = beC[lane],      c1 = beC[16 + lane], c2 = beC[32 + lane], c3 = beC[48 + lane];
    float c4 = beC[64 + lane], c5 = beC[80 + lane], c6 = beC[96 + lane];
    float acc = 0.f;
    int s0 = off[n], s1 = off[n + 1];
    for (int idx = s0; idx < s1; ++idx) {
        float ev = (float)(em[idx] & 0xffffu) * (1.0f / 65535.0f);
        float P = c6;
        P = c5 + (ev - 5.f / 6.f) * P;
        P = c4 + (ev - 4.f / 6.f) * P;
        P = c3 + (ev - 3.f / 6.f) * P;
        P = c2 + (ev - 2.f / 6.f) * P;
        P = c1 + (ev - 1.f / 6.f) * P;
        P = c0 + ev * P;
        acc += P;
    }
    mBE[(size_t)n * 16 + lane] = acc;
}

__device__ __forceinline__ void accum_edge(unsigned w, float hv, bool valid,
                                           float& G0, float& G1, float& G2, float& G3,
                                           float& G4, float& G5, float& G6) {
    float ev = (float)(w & 0xffffu) * (1.0f / 65535.0f);
    float h  = valid ? hv : 0.f;
    float n1 = ev;
    float n2 = n1 * (ev - 1.f / 6.f);
    float n3 = n2 * (ev - 2.f / 6.f);
    float n4 = n3 * (ev - 3.f / 6.f);
    float n5 = n4 * (ev - 4.f / 6.f);
    float n6 = n5 * (ev - 5.f / 6.f);
    G0 += h; G1 += n1 * h; G2 += n2 * h; G3 += n3 * h;
    G4 += n4 * h; G5 += n5 * h; G6 += n6 * h;
}

// ---------------------------------------------------------------------------
// Fused pass, poly basis, batch-4 software pipeline (em 2 batches ahead,
// h 1 batch ahead -> h address never waits on an em issued this iteration).
// ---------------------------------------------------------------------------
__global__ __launch_bounds__(256) void edge_gru_poly(
        const float* __restrict__ Cg, const unsigned* __restrict__ em,
        const int* __restrict__ off, const int* __restrict__ perm,
        const float* __restrict__ mBE,
        const float* __restrict__ hOld, float* __restrict__ hNew,
        const float* __restrict__ Wx, const float* __restrict__ Uh,
        const float* __restrict__ bx, const float* __restrict__ bh) {
    __shared__ float sC[7][16][17];
    __shared__ float sG[16][7][16];
    __shared__ float sWx[768], sUh[768], sb[96];
    __shared__ float sm[16][16], sh[16][16];

    for (int i = threadIdx.x; i < 7 * 256; i += 256) {
        int p = i >> 8, jj = i & 255;
        sC[p][jj >> 4][jj & 15] = Cg[i];
    }
    for (int i = threadIdx.x; i < 768; i += 256) { sWx[i] = Wx[i]; sUh[i] = Uh[i]; }
    if (threadIdx.x < 96)
        sb[threadIdx.x] = (threadIdx.x < 48) ? bx[threadIdx.x] : bh[threadIdx.x - 48];
    __syncthreads();

    int lane = threadIdx.x & 15;
    int grp  = threadIdx.x >> 4;
    int n = perm[blockIdx.x * 16 + grp];
    float hn = hOld[(size_t)n * 16 + lane];
    sh[grp][lane] = hn;

    float G0 = 0.f, G1 = 0.f, G2 = 0.f, G3 = 0.f, G4 = 0.f, G5 = 0.f, G6 = 0.f;
    int s0 = off[n], s1 = off[n + 1];

    int idx = s0;
    unsigned ce0 = (idx     < s1) ? em[idx]     : 0u;
    unsigned ce1 = (idx + 1 < s1) ? em[idx + 1] : 0u;
    unsigned ce2 = (idx + 2 < s1) ? em[idx + 2] : 0u;
    unsigned ce3 = (idx + 3 < s1) ? em[idx + 3] : 0u;
    float ch0 = hOld[(size_t)(ce0 >> 16) * 16 + lane];
    float ch1 = hOld[(size_t)(ce1 >> 16) * 16 + lane];
    float ch2 = hOld[(size_t)(ce2 >> 16) * 16 + lane];
    float ch3 = hOld[(size_t)(ce3 >> 16) * 16 + lane];
    unsigned ne0 = (idx + 4 < s1) ? em[idx + 4] : 0u;
    unsigned ne1 = (idx + 5 < s1) ? em[idx + 5] : 0u;
    unsigned ne2 = (idx + 6 < s1) ? em[idx + 6] : 0u;
    unsigned ne3 = (idx + 7 < s1) ? em[idx + 7] : 0u;

    while (idx < s1) {
        float nh0 = hOld[(size_t)(ne0 >> 16) * 16 + lane];
        float nh1 = hOld[(size_t)(ne1 >> 16) * 16 + lane];
        float nh2 = hOld[(size_t)(ne2 >> 16) * 16 + lane];
        float nh3 = hOld[(size_t)(ne3 >> 16) * 16 + lane];
        unsigned pe0 = (idx + 8  < s1) ? em[idx + 8]  : 0u;
        unsigned pe1 = (idx + 9  < s1) ? em[idx + 9]  : 0u;
        unsigned pe2 = (idx + 10 < s1) ? em[idx + 10] : 0u;
        unsigned pe3 = (idx + 11 < s1) ? em[idx + 11] : 0u;

        accum_edge(ce0, ch0, true,         G0, G1, G2, G3, G4, G5, G6);
        accum_edge(ce1, ch1, idx + 1 < s1, G0, G1, G2, G3, G4, G5, G6);
        accum_edge(ce2, ch2, idx + 2 < s1, G0, G1, G2, G3, G4, G5, G6);
        accum_edge(ce3, ch3, idx + 3 < s1, G0, G1, G2, G3, G4, G5, G6);

        ce0 = ne0; ce1 = ne1; ce2 = ne2; ce3 = ne3;
        ch0 = nh0; ch1 = nh1; ch2 = nh2; ch3 = nh3;
        ne0 = pe0; ne1 = pe1; ne2 = pe2; ne3 = pe3;
        idx += 4;
    }

    sG[grp][0][lane] = G0; sG[grp][1][lane] = G1; sG[grp][2][lane] = G2;
    sG[grp][3][lane] = G3; sG[grp][4][lane] = G4; sG[grp][5][lane] = G5;
    sG[grp][6][lane] = G6;

    float mi = mBE[(size_t)n * 16 + lane];
    #pragma unroll
    for (int p = 0; p < 7; ++p) {
        #pragma unroll
        for (int k = 0; k < 16; ++k)
            mi += sC[p][lane][k] * sG[grp][p][k];
    }
    sm[grp][lane] = mi;

    float xz = sb[lane], xr = sb[16 + lane], xh = sb[32 + lane];
    float hz = sb[48 + lane], hr = sb[64 + lane], hhp = sb[80 + lane];
    #pragma unroll
    for (int k = 0; k < 16; ++k) {
        float mk = sm[grp][k], hk = sh[grp][k];
        xz  += mk * sWx[k * 48 + lane];
        xr  += mk * sWx[k * 48 + 16 + lane];
        xh  += mk * sWx[k * 48 + 32 + lane];
        hz  += hk * sUh[k * 48 + lane];
        hr  += hk * sUh[k * 48 + 16 + lane];
        hhp += hk * sUh[k * 48 + 32 + lane];
    }
    float z  = sigmoid_f(xz + hz);
    float r  = sigmoid_f(xr + hr);
    float hc = tanhf(xh + r * hhp);
    hNew[(size_t)n * 16 + lane] = z * hn + (1.f - z) * hc;
}

// ---------------------------------------------------------------------------
// Readout: layer 1 fp32 VALU; layer 2 = two 32x128x128 GEMMs per block via
// MFMA 16x16x32 bf16 with hi/lo split (3 products ~ fp32 accuracy).
// ---------------------------------------------------------------------------
__global__ __launch_bounds__(256) void readout(
        const float* __restrict__ h, const float* __restrict__ x,
        const int* __restrict__ segment,
        const float* __restrict__ W_i, const float* __restrict__ b_i,
        const float* __restrict__ b_R,
        const float* __restrict__ W_j1, const float* __restrict__ b_j1,
        const float* __restrict__ b_j2,
        const ushort_t* __restrict__ WRh, const ushort_t* __restrict__ WRl,
        const ushort_t* __restrict__ WJh, const ushort_t* __restrict__ WJl,
        float* __restrict__ nb) {
    __shared__ __align__(16) ushort_t A[4][32][136];   // ilH, ilL, jlH, jlL; 272B row stride
    __shared__ float hx[32][19];
    __shared__ int   seg[32];
    float (*prod)[132] = (float (*)[132]) & A[0][0][0];   // overlay after MFMA

    int node0 = blockIdx.x * RO;
    int nn = min(RO, N_NODES - node0);
    int tid = threadIdx.x;

    for (int idx = tid; idx < RO * 18; idx += 256) {
        int n = idx / 18, k = idx % 18;
        float v = 0.f;
        if (n < nn)
            v = (k < 16) ? h[(size_t)(node0 + n) * 16 + k]
                         : x[(size_t)(node0 + n) * 2 + (k - 16)];
        hx[n][k] = v;
    }
    if (tid < 32) seg[tid] = segment[min(node0 + tid, N_NODES - 1)];
    __syncthreads();

    // ---- layer 1 (fp32), write hi/lo bf16 A-tiles ----
    int j = tid & 127, half = tid >> 7;
    {
        const float* W1 = half ? W_j1 : W_i;
        float bv = half ? b_j1[j] : b_i[j];
        float acc[RO];
        #pragma unroll
        for (int n = 0; n < RO; ++n) acc[n] = bv;
        for (int k = 0; k < 18; ++k) {
            float w = W1[k * RN + j];
            #pragma unroll
            for (int n = 0; n < RO; ++n) acc[n] += hx[n][k] * w;
        }
        int aH = half * 2, aL = half * 2 + 1;
        #pragma unroll
        for (int n = 0; n < RO; ++n) {
            float act = half ? selu_f(acc[n]) : tanhf(acc[n]);
            ushort_t hi = bf_rne(act);
            A[aH][n][j] = hi;
            A[aL][n][j] = bf_rne(act - bf_tof(hi));
        }
    }
    __syncthreads();

    // ---- layer 2: MFMA ----
    int wv = tid >> 6;          // wave 0..3
    int l  = tid & 63;
    int mt = wv & 1;            // M-tile (nodes 0-15 / 16-31)
    int ng = wv >> 1;           // N-group: N-tiles ng*4 .. ng*4+3
    int lr = l & 15, lg = l >> 4;

    f32x4 accR[4], accJ[4];
    #pragma unroll
    for (int t = 0; t < 4; ++t) {
        accR[t] = (f32x4){0.f, 0.f, 0.f, 0.f};
        accJ[t] = (f32x4){0.f, 0.f, 0.f, 0.f};
    }

    #pragma unroll
    for (int ks = 0; ks < 4; ++ks) {
        int arow = mt * 16 + lr;
        int kof  = ks * 32 + lg * 8;
        short8 aIH = *(const short8*)&A[0][arow][kof];
        short8 aIL = *(const short8*)&A[1][arow][kof];
        short8 aJH = *(const short8*)&A[2][arow][kof];
        short8 aJL = *(const short8*)&A[3][arow][kof];
        #pragma unroll
        for (int nt = 0; nt < 4; ++nt) {
            int col = (ng * 4 + nt) * 16 + lr;
            short8 bRH = *(const short8*)&WRh[col * 128 + kof];
            short8 bRL = *(const short8*)&WRl[col * 128 + kof];
            accR[nt] = MFMA16(aIH, bRH, accR[nt]);
            accR[nt] = MFMA16(aIH, bRL, accR[nt]);
            accR[nt] = MFMA16(aIL, bRH, accR[nt]);
            short8 bJH = *(const short8*)&WJh[col * 128 + kof];
            short8 bJL = *(const short8*)&WJl[col * 128 + kof];
            accJ[nt] = MFMA16(aJH, bJH, accJ[nt]);
            accJ[nt] = MFMA16(aJH, bJL, accJ[nt]);
            accJ[nt] = MFMA16(aJL, bJH, accJ[nt]);
        }
    }
    __syncthreads();   // all waves done reading A before prod overlay

    // epilogue: prod[node][j] = sigmoid(R + b_R) * (J + b_j2)
    #pragma unroll
    for (int nt = 0; nt < 4; ++nt) {
        int col = (ng * 4 + nt) * 16 + lr;
        float br = b_R[col];
        float bj = b_j2[col];
        #pragma unroll
        for (int r = 0; r < 4; ++r) {
            int node = mt * 16 + lg * 4 + r;
            prod[node][col] = sigmoid_f(accR[nt][r] + br) * (accJ[nt][r] + bj);
        }
    }
    __syncthreads();

    // segment-sum (sorted segments -> register accumulate, atomic on change)
    if (half == 0) {
        float a = 0.f;
        int cur = seg[0];
        for (int n = 0; n < nn; ++n) {
            int sg = seg[n];
            if (sg != cur) { atomicAdd(&nb[(size_t)cur * RN + j], a); a = 0.f; cur = sg; }
            a += prod[n][j];
        }
        atomicAdd(&nb[(size_t)cur * RN + j], a);
    }
}

__global__ void final_head(const float* __restrict__ nb, const float* __restrict__ W_f1,
                           const float* __restrict__ b_f1, const float* __restrict__ W_f2,
                           const float* __restrict__ b_f2, float* __restrict__ out) {
    __shared__ float row[128];
    __shared__ float red[128];
    int g = blockIdx.x, j = threadIdx.x;
    row[j] = nb[(size_t)g * 128 + j];
    __syncthreads();
    float a = b_f1[j];
    for (int k = 0; k < 128; ++k)
        a += row[k] * W_f1[k * 128 + j];
    red[j] = selu_f(a) * W_f2[j];
    __syncthreads();
    for (int s2 = 64; s2 > 0; s2 >>= 1) {
        if (j < s2) red[j] += red[j + s2];
        __syncthreads();
    }
    if (j == 0) out[g] = red[0] + b_f2[0];
}

extern "C" void kernel_launch(void* const* d_in, const int* in_sizes, int n_in,
                              void* d_out, int out_size, void* d_ws, size_t ws_size,
                              hipStream_t stream) {
    const float* x    = (const float*)d_in[0];
    const float* e    = (const float*)d_in[1];
    const float* W_l1 = (const float*)d_in[2];
    const float* b_l1 = (const float*)d_in[3];
    const float* W_l2 = (const float*)d_in[4];
    const float* b_l2 = (const float*)d_in[5];
    const float* W_b1 = (const float*)d_in[6];
    const float* b_b1 = (const float*)d_in[7];
    const float* W_b2 = (const float*)d_in[8];
    const float* b_b2 = (const float*)d_in[9];
    const float* gWx  = (const float*)d_in[10];
    const float* gUh  = (const float*)d_in[11];
    const float* gbx  = (const float*)d_in[12];
    const float* gbh  = (const float*)d_in[13];
    const float* W_i  = (const float*)d_in[14];
    const float* b_i  = (const float*)d_in[15];
    const float* W_R  = (const float*)d_in[16];
    const float* b_R  = (const float*)d_in[17];
    const float* W_j1 = (const float*)d_in[18];
    const float* b_j1 = (const float*)d_in[19];
    const float* W_j2 = (const float*)d_in[20];
    const float* b_j2 = (const float*)d_in[21];
    const float* W_f1 = (const float*)d_in[22];
    const float* b_f1 = (const float*)d_in[23];
    const float* W_f2 = (const float*)d_in[24];
    const float* b_f2 = (const float*)d_in[25];
    const int* first   = (const int*)d_in[26];
    const int* second  = (const int*)d_in[27];
    const int* segment = (const int*)d_in[28];
    float* out = (float*)d_out;

    float* ws   = (float*)d_ws;
    float* aT   = ws;                               // 1792
    float* beT  = aT + 1792;                        // 112
    float* Cg   = beT + 112;                        // 1792
    float* beC  = Cg + 1792;                        // 112 -> 3808 total (16B-mult)
    float* mBE  = beC + 112;                        // 800000
    float* hA   = mBE + 800000;                     // 800000
    float* hB   = hA + 800000;                      // 800000
    float* nb   = hB + 800000;                      // 64000
    ushort_t* WRh = (ushort_t*)(nb + 64000);        // 16384 ushort = 8192 floats
    ushort_t* WRl = WRh + 16384;
    ushort_t* WJh = WRl + 16384;
    ushort_t* WJl = WJh + 16384;
    int*   deg  = (int*)(WJl + 16384);              // 50000
    int*   dh   = deg + N_NODES;                    // 64 (memset together with deg)
    int*   incl = dh + 64;                          // 50000
    int*   off  = incl + N_NODES;                   // 50001
    int*   cur  = off + N_NODES + 1;                // 50000
    int*   bsum = cur + N_NODES;                    // 256
    int*   bpre = bsum + 256;                       // 256
    int*   dcur = bpre + 256;                       // 64
    int*   perm = dcur + 64;                        // 50000
    unsigned* em = (unsigned*)(perm + N_NODES);     // 800000

    const int NBLK = (N_NODES + 255) / 256;         // 196

    build_and_prep<<<7 + 64, 256, 0, stream>>>(W_l1, b_l1, W_l2, b_l2,
                                               W_b1, b_b1, W_b2, b_b2,
                                               W_R, W_j2, aT, beT, WRh, WRl, WJh, WJl);
    newton_coeffs<<<1, 256, 0, stream>>>(aT, beT, Cg, beC);
    init_h<<<NBLK, 256, 0, stream>>>(x, hA);

    hipMemsetAsync(deg, 0, (N_NODES + 64) * sizeof(int), stream);
    count_deg<<<N_EDGES / 256, 256, 0, stream>>>(second, deg);
    scan1<<<NBLK, 256, 0, stream>>>(deg, incl, bsum, dh);
    scan2<<<1, 256, 0, stream>>>(bsum, bpre, NBLK, dh, dcur);
    scan3<<<NBLK, 256, 0, stream>>>(incl, deg, bpre, off, cur, dcur, perm);
    scatter_edges<<<N_EDGES / 256, 256, 0, stream>>>(e, first, second, cur, em);
    mbe_pass<<<N_NODES / 16, 256, 0, stream>>>(beC, em, off, perm, mBE);

    float* hc = hA;
    float* hn = hB;
    for (int p = 0; p < 8; ++p) {
        edge_gru_poly<<<N_NODES / 16, 256, 0, stream>>>(Cg, em, off, perm, mBE,
                                                        hc, hn, gWx, gUh, gbx, gbh);
        float* tmp = hc; hc = hn; hn = tmp;
    }

    hipMemsetAsync(nb, 0, (size_t)N_GRAPHS * 128 * sizeof(float), stream);
    readout<<<(N_NODES + RO - 1) / RO, 256, 0, stream>>>(
        hc, x, segment, W_i, b_i, b_R, W_j1, b_j1, b_j2,
        WRh, WRl, WJh, WJl, nb);
    final_head<<<N_GRAPHS, 128, 0, stream>>>(nb, W_f1, b_f1, W_f2, b_f2, out);
}

// Round 7
// 611.870 us; speedup vs baseline: 1.3588x; 1.3588x over previous
//
#include <hip/hip_runtime.h>
#include <math.h>

#define N_NODES  50000
#define N_EDGES  800000
#define N_GRAPHS 500
#define NH       16
#define MHID     256
#define RN       128
#define RO       32
#define DDEG     6

typedef unsigned short ushort_t;
typedef __attribute__((ext_vector_type(8))) short short8;
typedef __attribute__((ext_vector_type(4))) float f32x4;

__device__ __forceinline__ float selu_f(float v) {
    const float scale = 1.0507009873554805f;
    const float alpha = 1.6732632423543772f;
    return v > 0.f ? scale * v : scale * alpha * (expf(v) - 1.f);
}
__device__ __forceinline__ float sigmoid_f(float v) { return 1.f / (1.f + expf(-v)); }
__device__ __forceinline__ ushort_t bf_rne(float v) {
    unsigned u = __float_as_uint(v);
    return (ushort_t)((u + 0x7fffu + ((u >> 16) & 1u)) >> 16);
}
__device__ __forceinline__ float bf_tof(ushort_t s) {
    return __uint_as_float(((unsigned)s) << 16);
}
#define MFMA16(a, b, c) __builtin_amdgcn_mfma_f32_16x16x32_bf16(a, b, c, 0, 0, 0)

// ---------------------------------------------------------------------------
// blocks 0..6: exact MLP eval at nodes e=k/6 -> aT[7][256], beT[7][16].
// blocks 7..70: transpose+split W_R, W_j2 into bf16 hi/lo [j][k] for MFMA B.
// ---------------------------------------------------------------------------
__global__ void build_and_prep(const float* __restrict__ W_l1, const float* __restrict__ b_l1,
                               const float* __restrict__ W_l2, const float* __restrict__ b_l2,
                               const float* __restrict__ W_b1, const float* __restrict__ b_b1,
                               const float* __restrict__ W_b2, const float* __restrict__ b_b2,
                               const float* __restrict__ W_R, const float* __restrict__ W_j2,
                               float* __restrict__ aT, float* __restrict__ beT,
                               ushort_t* __restrict__ WRh, ushort_t* __restrict__ WRl,
                               ushort_t* __restrict__ WJh, ushort_t* __restrict__ WJl) {
    __shared__ float hid[MHID];
    __shared__ float hidb[MHID];
    int j = threadIdx.x;
    if (blockIdx.x < 7) {
        int t = blockIdx.x;
        float ev = (float)t / 6.0f;
        hid[j]  = selu_f(ev * W_l1[j] + b_l1[j]);
        hidb[j] = selu_f(ev * W_b1[j] + b_b1[j]);
        __syncthreads();
        float acc = b_l2[j];
        for (int k = 0; k < MHID; ++k)
            acc += hid[k] * W_l2[k * 256 + j];
        aT[t * 256 + j] = acc;
        if (j < NH) {
            float accb = b_b2[j];
            for (int k = 0; k < MHID; ++k)
                accb += hidb[k] * W_b2[k * NH + j];
            beT[t * NH + j] = accb;
        }
    } else {
        int g = (blockIdx.x - 7) * 256 + j;     // 0..16383
        int jj = g >> 7, kk = g & 127;
        float v = W_R[kk * 128 + jj];
        ushort_t h = bf_rne(v);
        WRh[jj * 128 + kk] = h;
        WRl[jj * 128 + kk] = bf_rne(v - bf_tof(h));
        v = W_j2[kk * 128 + jj];
        h = bf_rne(v);
        WJh[jj * 128 + kk] = h;
        WJl[jj * 128 + kk] = bf_rne(v - bf_tof(h));
    }
}

// Newton divided-difference coefficients over nodes k/6.
__global__ void newton_coeffs(const float* __restrict__ aT, const float* __restrict__ beT,
                              float* __restrict__ C, float* __restrict__ beC) {
    int j = threadIdx.x;
    float y[7];
    #pragma unroll
    for (int k = 0; k < 7; ++k) y[k] = aT[k * 256 + j];
    #pragma unroll
    for (int lvl = 1; lvl <= DDEG; ++lvl)
        #pragma unroll
        for (int k = DDEG; k >= 1; --k)
            if (k >= lvl) y[k] = (y[k] - y[k - 1]) * (6.0f / (float)lvl);
    #pragma unroll
    for (int p = 0; p < 7; ++p) C[p * 256 + j] = y[p];

    if (j < NH) {
        float z[7];
        #pragma unroll
        for (int k = 0; k < 7; ++k) z[k] = beT[k * NH + j];
        #pragma unroll
        for (int lvl = 1; lvl <= DDEG; ++lvl)
            #pragma unroll
            for (int k = DDEG; k >= 1; --k)
                if (k >= lvl) z[k] = (z[k] - z[k - 1]) * (6.0f / (float)lvl);
        #pragma unroll
        for (int p = 0; p < 7; ++p) beC[p * NH + j] = z[p];
    }
}

__global__ void init_h(const float* __restrict__ x, float* __restrict__ h) {
    int n = blockIdx.x * blockDim.x + threadIdx.x;
    if (n >= N_NODES) return;
    float4* hp = (float4*)(h + (size_t)n * 16);
    hp[0] = make_float4(x[n * 2 + 0], x[n * 2 + 1], 0.f, 0.f);
    hp[1] = make_float4(0.f, 0.f, 0.f, 0.f);
    hp[2] = make_float4(0.f, 0.f, 0.f, 0.f);
    hp[3] = make_float4(0.f, 0.f, 0.f, 0.f);
}

// ---------------------------------------------------------------------------
// CSR-by-destination build
// ---------------------------------------------------------------------------
__global__ void count_deg(const int* __restrict__ second, int* __restrict__ deg) {
    int i = blockIdx.x * blockDim.x + threadIdx.x;
    if (i < N_EDGES) atomicAdd(&deg[second[i]], 1);
}

__global__ void scan1(const int* __restrict__ deg, int* __restrict__ incl, int* __restrict__ bsum) {
    __shared__ int s[256];
    int t = threadIdx.x, i = blockIdx.x * 256 + t;
    int v = (i < N_NODES) ? deg[i] : 0;
    s[t] = v;
    __syncthreads();
    for (int d = 1; d < 256; d <<= 1) {
        int add = (t >= d) ? s[t - d] : 0;
        __syncthreads();
        s[t] += add;
        __syncthreads();
    }
    if (i < N_NODES) incl[i] = s[t];
    if (t == 255) bsum[blockIdx.x] = s[255];
}

__global__ void scan2(const int* __restrict__ bsum, int* __restrict__ bpre, int nblk) {
    __shared__ int s[256];
    int t = threadIdx.x;
    int v = (t < nblk) ? bsum[t] : 0;
    s[t] = v;
    __syncthreads();
    for (int d = 1; d < 256; d <<= 1) {
        int add = (t >= d) ? s[t - d] : 0;
        __syncthreads();
        s[t] += add;
        __syncthreads();
    }
    if (t < nblk) bpre[t] = s[t] - v;   // exclusive
}

__global__ void scan3(const int* __restrict__ incl, const int* __restrict__ deg,
                      const int* __restrict__ bpre, int* __restrict__ off, int* __restrict__ cursor) {
    int i = blockIdx.x * 256 + threadIdx.x;
    if (i < N_NODES) {
        int o = bpre[blockIdx.x] + incl[i] - deg[i];
        off[i] = o;
        cursor[i] = o;
    }
    if (i == 0) off[N_NODES] = N_EDGES;
}

// em word = (first << 16) | round(e * 65535)
__global__ void scatter_edges(const float* __restrict__ e, const int* __restrict__ first,
                              const int* __restrict__ second, int* __restrict__ cursor,
                              unsigned* __restrict__ em) {
    int i = blockIdx.x * blockDim.x + threadIdx.x;
    if (i >= N_EDGES) return;
    int d = second[i];
    int slot = atomicAdd(&cursor[d], 1);
    unsigned e16 = (unsigned)(e[i] * 65535.f + 0.5f);
    em[slot] = ((unsigned)first[i] << 16) | e16;
}

// ---------------------------------------------------------------------------
// Fused pass, chunk-16: lane-parallel em load (contiguous, no dependency),
// shfl-broadcast, 16 INDEPENDENT h gathers per chunk -> 2 L2 RTs per chunk
// instead of 1 per edge. be-term folded via basis sums S_p (pass-invariant
// math, recomputed cheaply). Then recombination + GRU. Zero atomics.
// ---------------------------------------------------------------------------
__global__ __launch_bounds__(256) void edge_gru_chunk(
        const float* __restrict__ Cg, const float* __restrict__ beC,
        const unsigned* __restrict__ em, const int* __restrict__ off,
        const float* __restrict__ hOld, float* __restrict__ hNew,
        const float* __restrict__ Wx, const float* __restrict__ Uh,
        const float* __restrict__ bx, const float* __restrict__ bh) {
    __shared__ float sC[7][16][17];     // stride 17: conflict-free lane reads
    __shared__ float sBC[7][16];
    __shared__ float sWx[768], sUh[768], sb[96];
    __shared__ float sG[16][7][18];     // grp stride 126 words: ~conflict-free broadcasts
    __shared__ float sm[16][17], sh[16][17];

    for (int i = threadIdx.x; i < 7 * 256; i += 256) {
        int p = i >> 8, jj = i & 255;
        sC[p][jj >> 4][jj & 15] = Cg[i];
    }
    if (threadIdx.x < 112) sBC[threadIdx.x >> 4][threadIdx.x & 15] = beC[threadIdx.x];
    for (int i = threadIdx.x; i < 768; i += 256) { sWx[i] = Wx[i]; sUh[i] = Uh[i]; }
    if (threadIdx.x < 96)
        sb[threadIdx.x] = (threadIdx.x < 48) ? bx[threadIdx.x] : bh[threadIdx.x - 48];
    __syncthreads();

    int lane = threadIdx.x & 15;
    int grp  = threadIdx.x >> 4;
    int n = blockIdx.x * 16 + grp;            // grid 3125 exact
    float hn = hOld[(size_t)n * 16 + lane];
    sh[grp][lane] = hn;

    int s0 = off[n], s1 = off[n + 1];
    float G0=0.f,G1=0.f,G2=0.f,G3=0.f,G4=0.f,G5=0.f,G6=0.f;
    float S0=0.f,S1=0.f,S2=0.f,S3=0.f,S4=0.f,S5=0.f,S6=0.f;

    int nch = (s1 - s0 + 15) >> 4;
    unsigned myem = 0u;
    if (s0 < s1) myem = em[min(s0 + lane, s1 - 1)];
    for (int c = 0; c < nch; ++c) {
        int base = s0 + (c << 4);
        unsigned nxt = 0u;
        if (base + 16 < s1) nxt = em[min(base + 16 + lane, s1 - 1)];
        int rem = s1 - base;                  // >0
        #pragma unroll
        for (int k = 0; k < 16; ++k) {
            unsigned w = __shfl(myem, k, 16);
            float hv = hOld[(size_t)(w >> 16) * 16 + lane];
            float msk = (k < rem) ? 1.f : 0.f;
            float ev = (float)(w & 0xffffu) * (1.0f / 65535.0f);
            float n1 = ev;
            float n2 = n1 * (ev - 1.f / 6.f);
            float n3 = n2 * (ev - 2.f / 6.f);
            float n4 = n3 * (ev - 3.f / 6.f);
            float n5 = n4 * (ev - 4.f / 6.f);
            float n6 = n5 * (ev - 5.f / 6.f);
            float hm = hv * msk;
            G0 += hm;      G1 += n1 * hm; G2 += n2 * hm; G3 += n3 * hm;
            G4 += n4 * hm; G5 += n5 * hm; G6 += n6 * hm;
            S0 += msk;      S1 += n1 * msk; S2 += n2 * msk; S3 += n3 * msk;
            S4 += n4 * msk; S5 += n5 * msk; S6 += n6 * msk;
        }
        myem = nxt;
    }

    // publish G (same-wave lockstep)
    sG[grp][0][lane]=G0; sG[grp][1][lane]=G1; sG[grp][2][lane]=G2; sG[grp][3][lane]=G3;
    sG[grp][4][lane]=G4; sG[grp][5][lane]=G5; sG[grp][6][lane]=G6;

    // be-term from basis sums + C-recombination
    float mi = sBC[0][lane]*S0 + sBC[1][lane]*S1 + sBC[2][lane]*S2 + sBC[3][lane]*S3
             + sBC[4][lane]*S4 + sBC[5][lane]*S5 + sBC[6][lane]*S6;
    #pragma unroll
    for (int p = 0; p < 7; ++p) {
        #pragma unroll
        for (int k = 0; k < 16; ++k)
            mi += sC[p][lane][k] * sG[grp][p][k];
    }
    sm[grp][lane] = mi;

    // GRU (reset_after=True)
    float xz = sb[lane], xr = sb[16 + lane], xh = sb[32 + lane];
    float hz = sb[48 + lane], hr = sb[64 + lane], hhp = sb[80 + lane];
    #pragma unroll
    for (int k = 0; k < 16; ++k) {
        float mk = sm[grp][k], hk = sh[grp][k];
        xz  += mk * sWx[k * 48 + lane];
        xr  += mk * sWx[k * 48 + 16 + lane];
        xh  += mk * sWx[k * 48 + 32 + lane];
        hz  += hk * sUh[k * 48 + lane];
        hr  += hk * sUh[k * 48 + 16 + lane];
        hhp += hk * sUh[k * 48 + 32 + lane];
    }
    float z  = sigmoid_f(xz + hz);
    float r  = sigmoid_f(xr + hr);
    float hc = tanhf(xh + r * hhp);
    hNew[(size_t)n * 16 + lane] = z * hn + (1.f - z) * hc;
}

// ---------------------------------------------------------------------------
// Readout: layer 1 fp32 VALU; layer 2 MFMA (R6-verified indexing), loop
// structure reworked to avoid B-load hoisting/spills: ks `unroll 1`,
// R-GEMM then J-GEMM sequentially.
// ---------------------------------------------------------------------------
__global__ __launch_bounds__(256) void readout(
        const float* __restrict__ h, const float* __restrict__ x,
        const int* __restrict__ segment,
        const float* __restrict__ W_i, const float* __restrict__ b_i,
        const float* __restrict__ b_R,
        const float* __restrict__ W_j1, const float* __restrict__ b_j1,
        const float* __restrict__ b_j2,
        const ushort_t* __restrict__ WRh, const ushort_t* __restrict__ WRl,
        const ushort_t* __restrict__ WJh, const ushort_t* __restrict__ WJl,
        float* __restrict__ nb) {
    __shared__ __align__(16) ushort_t A[4][32][136];   // ilH, ilL, jlH, jlL
    __shared__ float hx[32][19];
    __shared__ int   seg[32];
    float (*prod)[132] = (float (*)[132]) & A[0][0][0];   // overlay after MFMA

    int node0 = blockIdx.x * RO;
    int nn = min(RO, N_NODES - node0);
    int tid = threadIdx.x;

    for (int idx = tid; idx < RO * 18; idx += 256) {
        int n = idx / 18, k = idx % 18;
        float v = 0.f;
        if (n < nn)
            v = (k < 16) ? h[(size_t)(node0 + n) * 16 + k]
                         : x[(size_t)(node0 + n) * 2 + (k - 16)];
        hx[n][k] = v;
    }
    if (tid < 32) seg[tid] = segment[min(node0 + tid, N_NODES - 1)];
    __syncthreads();

    // ---- layer 1 (fp32), write hi/lo bf16 A-tiles ----
    int j = tid & 127, half = tid >> 7;
    {
        const float* W1 = half ? W_j1 : W_i;
        float bv = half ? b_j1[j] : b_i[j];
        float acc[RO];
        #pragma unroll
        for (int n = 0; n < RO; ++n) acc[n] = bv;
        for (int k = 0; k < 18; ++k) {
            float w = W1[k * RN + j];
            #pragma unroll
            for (int n = 0; n < RO; ++n) acc[n] += hx[n][k] * w;
        }
        int aH = half * 2, aL = half * 2 + 1;
        #pragma unroll
        for (int n = 0; n < RO; ++n) {
            float act = half ? selu_f(acc[n]) : tanhf(acc[n]);
            ushort_t hi = bf_rne(act);
            A[aH][n][j] = hi;
            A[aL][n][j] = bf_rne(act - bf_tof(hi));
        }
    }
    __syncthreads();

    // ---- layer 2: MFMA, R then J ----
    int wv = tid >> 6;          // wave 0..3
    int l  = tid & 63;
    int mt = wv & 1;            // M-tile (nodes 0-15 / 16-31)
    int ng = wv >> 1;           // N-group: N-tiles ng*4 .. ng*4+3
    int lr = l & 15, lg = l >> 4;

    f32x4 accR[4], accJ[4];
    #pragma unroll
    for (int t = 0; t < 4; ++t) {
        accR[t] = (f32x4){0.f, 0.f, 0.f, 0.f};
        accJ[t] = (f32x4){0.f, 0.f, 0.f, 0.f};
    }

    #pragma unroll 1
    for (int ks = 0; ks < 4; ++ks) {
        int arow = mt * 16 + lr;
        int kof  = ks * 32 + lg * 8;
        short8 aH = *(const short8*)&A[0][arow][kof];
        short8 aL = *(const short8*)&A[1][arow][kof];
        #pragma unroll
        for (int nt = 0; nt < 4; ++nt) {
            int col = (ng * 4 + nt) * 16 + lr;
            short8 bH = *(const short8*)&WRh[col * 128 + kof];
            short8 bL = *(const short8*)&WRl[col * 128 + kof];
            accR[nt] = MFMA16(aH, bH, accR[nt]);
            accR[nt] = MFMA16(aH, bL, accR[nt]);
            accR[nt] = MFMA16(aL, bH, accR[nt]);
        }
    }
    #pragma unroll 1
    for (int ks = 0; ks < 4; ++ks) {
        int arow = mt * 16 + lr;
        int kof  = ks * 32 + lg * 8;
        short8 aH = *(const short8*)&A[2][arow][kof];
        short8 aL = *(const short8*)&A[3][arow][kof];
        #pragma unroll
        for (int nt = 0; nt < 4; ++nt) {
            int col = (ng * 4 + nt) * 16 + lr;
            short8 bH = *(const short8*)&WJh[col * 128 + kof];
            short8 bL = *(const short8*)&WJl[col * 128 + kof];
            accJ[nt] = MFMA16(aH, bH, accJ[nt]);
            accJ[nt] = MFMA16(aH, bL, accJ[nt]);
            accJ[nt] = MFMA16(aL, bH, accJ[nt]);
        }
    }
    __syncthreads();   // all waves done reading A before prod overlay

    // epilogue: prod[node][j] = sigmoid(R + b_R) * (J + b_j2)
    #pragma unroll
    for (int nt = 0; nt < 4; ++nt) {
        int col = (ng * 4 + nt) * 16 + lr;
        float br = b_R[col];
        float bj = b_j2[col];
        #pragma unroll
        for (int r = 0; r < 4; ++r) {
            int node = mt * 16 + lg * 4 + r;
            prod[node][col] = sigmoid_f(accR[nt][r] + br) * (accJ[nt][r] + bj);
        }
    }
    __syncthreads();

    // segment-sum (sorted segments -> register accumulate, atomic on change)
    if (half == 0) {
        float a = 0.f;
        int cur = seg[0];
        for (int n = 0; n < nn; ++n) {
            int sg = seg[n];
            if (sg != cur) { atomicAdd(&nb[(size_t)cur * RN + j], a); a = 0.f; cur = sg; }
            a += prod[n][j];
        }
        atomicAdd(&nb[(size_t)cur * RN + j], a);
    }
}

__global__ void final_head(const float* __restrict__ nb, const float* __restrict__ W_f1,
                           const float* __restrict__ b_f1, const float* __restrict__ W_f2,
                           const float* __restrict__ b_f2, float* __restrict__ out) {
    __shared__ float row[128];
    __shared__ float red[128];
    int g = blockIdx.x, j = threadIdx.x;
    row[j] = nb[(size_t)g * 128 + j];
    __syncthreads();
    float a = b_f1[j];
    for (int k = 0; k < 128; ++k)
        a += row[k] * W_f1[k * 128 + j];
    red[j] = selu_f(a) * W_f2[j];
    __syncthreads();
    for (int s2 = 64; s2 > 0; s2 >>= 1) {
        if (j < s2) red[j] += red[j + s2];
        __syncthreads();
    }
    if (j == 0) out[g] = red[0] + b_f2[0];
}

extern "C" void kernel_launch(void* const* d_in, const int* in_sizes, int n_in,
                              void* d_out, int out_size, void* d_ws, size_t ws_size,
                              hipStream_t stream) {
    const float* x    = (const float*)d_in[0];
    const float* e    = (const float*)d_in[1];
    const float* W_l1 = (const float*)d_in[2];
    const float* b_l1 = (const float*)d_in[3];
    const float* W_l2 = (const float*)d_in[4];
    const float* b_l2 = (const float*)d_in[5];
    const float* W_b1 = (const float*)d_in[6];
    const float* b_b1 = (const float*)d_in[7];
    const float* W_b2 = (const float*)d_in[8];
    const float* b_b2 = (const float*)d_in[9];
    const float* gWx  = (const float*)d_in[10];
    const float* gUh  = (const float*)d_in[11];
    const float* gbx  = (const float*)d_in[12];
    const float* gbh  = (const float*)d_in[13];
    const float* W_i  = (const float*)d_in[14];
    const float* b_i  = (const float*)d_in[15];
    const float* W_R  = (const float*)d_in[16];
    const float* b_R  = (const float*)d_in[17];
    const float* W_j1 = (const float*)d_in[18];
    const float* b_j1 = (const float*)d_in[19];
    const float* W_j2 = (const float*)d_in[20];
    const float* b_j2 = (const float*)d_in[21];
    const float* W_f1 = (const float*)d_in[22];
    const float* b_f1 = (const float*)d_in[23];
    const float* W_f2 = (const float*)d_in[24];
    const float* b_f2 = (const float*)d_in[25];
    const int* first   = (const int*)d_in[26];
    const int* second  = (const int*)d_in[27];
    const int* segment = (const int*)d_in[28];
    float* out = (float*)d_out;

    float* ws   = (float*)d_ws;
    float* aT   = ws;                               // 1792
    float* beT  = aT + 1792;                        // 112
    float* Cg   = beT + 112;                        // 1792
    float* beC  = Cg + 1792;                        // 112 -> 3808 total
    float* hA   = beC + 112;                        // 800000
    float* hB   = hA + 800000;                      // 800000
    float* nb   = hB + 800000;                      // 64000
    ushort_t* WRh = (ushort_t*)(nb + 64000);        // 16384 ushort each
    ushort_t* WRl = WRh + 16384;
    ushort_t* WJh = WRl + 16384;
    ushort_t* WJl = WJh + 16384;
    int*   deg  = (int*)(WJl + 16384);              // 50000
    int*   incl = deg + N_NODES;                    // 50000
    int*   off  = incl + N_NODES;                   // 50001
    int*   cur  = off + N_NODES + 1;                // 50000
    int*   bsum = cur + N_NODES;                    // 256
    int*   bpre = bsum + 256;                       // 256
    unsigned* em = (unsigned*)(bpre + 256);         // 800000

    const int NBLK = (N_NODES + 255) / 256;         // 196

    build_and_prep<<<7 + 64, 256, 0, stream>>>(W_l1, b_l1, W_l2, b_l2,
                                               W_b1, b_b1, W_b2, b_b2,
                                               W_R, W_j2, aT, beT, WRh, WRl, WJh, WJl);
    newton_coeffs<<<1, 256, 0, stream>>>(aT, beT, Cg, beC);
    init_h<<<NBLK, 256, 0, stream>>>(x, hA);

    hipMemsetAsync(deg, 0, N_NODES * sizeof(int), stream);
    count_deg<<<N_EDGES / 256, 256, 0, stream>>>(second, deg);
    scan1<<<NBLK, 256, 0, stream>>>(deg, incl, bsum);
    scan2<<<1, 256, 0, stream>>>(bsum, bpre, NBLK);
    scan3<<<NBLK, 256, 0, stream>>>(incl, deg, bpre, off, cur);
    scatter_edges<<<N_EDGES / 256, 256, 0, stream>>>(e, first, second, cur, em);

    float* hc = hA;
    float* hn = hB;
    for (int p = 0; p < 8; ++p) {
        edge_gru_chunk<<<N_NODES / 16, 256, 0, stream>>>(Cg, beC, em, off,
                                                         hc, hn, gWx, gUh, gbx, gbh);
        float* tmp = hc; hc = hn; hn = tmp;
    }

    hipMemsetAsync(nb, 0, (size_t)N_GRAPHS * 128 * sizeof(float), stream);
    readout<<<(N_NODES + RO - 1) / RO, 256, 0, stream>>>(
        hc, x, segment, W_i, b_i, b_R, W_j1, b_j1, b_j2,
        WRh, WRl, WJh, WJl, nb);
    final_head<<<N_GRAPHS, 128, 0, stream>>>(nb, W_f1, b_f1, W_f2, b_f2, out);
}